// Round 9
// baseline (84373.944 us; speedup 1.0000x reference)
//
#include <hip/hip_runtime.h>

// B=16,S=1024,C=509->IN=512,H=600; bidirectional GRU, 16384 serial steps/dir.
//
// R6 (30.0ms, proven): 150 WG agent-scope u64 {ctr|f32} slot exchange, 2
// barriers + LDS per step -> 1.78us/step.
// R8 (44.8ms): XCD-local RMW exchange -- RMW line ping-pong beat the latency
// gain. Reverted.
// R9: wave-autonomous refinement of R6. No barriers / no LDS in the step
// loop: each of 600 waves owns 2 h elements (6 Whh rows in VGPRs), polls all
// 600 slots into registers (10/lane), 6x10 FMA + 6 shfl_xor reduce chains,
// lane0 gates+publishes 2 slots. Same slot protocol as R6 (agent scope).
//
// Workspace (R6 layout):
//   X  @0          16,777,216
//   GX @16,777,216 58,982,400 (fp16)   end 75,759,616
//   PB @75,776,000 [2][2][600]*8 = 19,200
//   DF @75,795,200 256
//   WB @75,795,456 1,843,200

#define HDIM   600
#define TH3    1800
#define NROWS  16384
#define KDIM   512
#define NSTEP  16384

#define OFF_GX 16777216ull
#define OFF_PB 75776000ull
#define OFF_DF 75795200ull
#define OFF_WB 75795456ull

typedef short bf16x8 __attribute__((ext_vector_type(8)));
typedef float f32x4  __attribute__((ext_vector_type(4)));
typedef _Float16 f16;
typedef unsigned long long u64;

__device__ __forceinline__ float bf2f(unsigned short u) {
  union { unsigned u32; float f; } v; v.u32 = ((unsigned)u) << 16; return v.f;
}
__device__ __forceinline__ unsigned short f2bf(float f) {
  union { float f; unsigned u; } v; v.f = f;
  unsigned r = (v.u + 0x7FFFu + ((v.u >> 16) & 1u)) >> 16;   // RNE
  return (unsigned short)r;
}

// ---- init: pub slots + dtype detect ---------------------------------------
__global__ void init_k(const unsigned short* __restrict__ ctx,
                       u64* __restrict__ pub, int* __restrict__ df) {
  int i = blockIdx.x * 256 + threadIdx.x;
  if (i < 2 * 2 * HDIM) {                      // [d][par][600]
    int par = (i / HDIM) & 1;
    pub[i] = par ? 0x00000000FFFFFFFFull : 0ull;   // par0: ctr=0,h=0 (step 0)
  }
  if (blockIdx.x == 0 && threadIdx.x == 0) {
    int bad = 0;
    for (int k = 0; k < 512; ++k) {
      unsigned e = (ctx[2 * k] >> 7) & 0xFFu;
      bad += (e >= 0xF0u) | (e < 0x10u);
    }
    df[0] = (bad > 0) ? 1 : 0;
  }
}

// ---- embed + concat -> X bf16 [16384][512] --------------------------------
__global__ void embed_k(const unsigned short* __restrict__ ctx,
                        const int* __restrict__ tags,
                        const unsigned short* __restrict__ temb,
                        unsigned short* __restrict__ x,
                        const int* __restrict__ df) {
  const int fp32 = df[0];
  int idx = blockIdx.x * 256 + threadIdx.x;
  int row = idx >> 9, j = idx & 511;
  unsigned short v;
  if (fp32) {
    const float* ctxF  = (const float*)ctx;
    const float* tembF = (const float*)temb;
    v = (j < 3) ? f2bf(tembF[tags[row] * 3 + j]) : f2bf(ctxF[row * 509 + (j - 3)]);
  } else {
    v = (j < 3) ? temb[tags[row] * 3 + j] : ctx[row * 509 + (j - 3)];
  }
  x[idx] = v;
}

// ---- W_ih -> bf16 ---------------------------------------------------------
__global__ void wcast_k(const unsigned short* __restrict__ wih,
                        unsigned short* __restrict__ wb,
                        const int* __restrict__ df) {
  const int fp32 = df[0];
  int i = blockIdx.x * 256 + threadIdx.x;
  wb[i] = fp32 ? f2bf(((const float*)wih)[i]) : wih[i];
}

// ---- GEMM: gx[16384][1800] = X @ W_ih^T + b_ih (fp16 out) -----------------
__global__ __launch_bounds__(256) void gemm_k(const unsigned short* __restrict__ X,
                                              const unsigned short* __restrict__ Wb,
                                              const unsigned short* __restrict__ bih,
                                              f16* __restrict__ gx,
                                              const int* __restrict__ df) {
  const int fp32 = df[0];
  const int lane = threadIdx.x & 63;
  const int wv   = threadIdx.x >> 6;
  const int mt   = blockIdx.y * 4 + wv;
  const int nt   = blockIdx.x;
  const int mrow = mt * 16 + (lane & 15);
  const int ncol = nt * 16 + (lane & 15);
  const int koff = (lane >> 4) * 8;
  const int nclamp = (ncol < TH3) ? ncol : (TH3 - 1);

  const bf16x8* ap = (const bf16x8*)(X  + (size_t)mrow   * KDIM + koff);
  const bf16x8* bp = (const bf16x8*)(Wb + (size_t)nclamp * KDIM + koff);

  f32x4 acc = {0.f, 0.f, 0.f, 0.f};
  #pragma unroll
  for (int kc = 0; kc < 16; ++kc) {
    bf16x8 av = ap[kc * 4];
    bf16x8 bv = bp[kc * 4];
    acc = __builtin_amdgcn_mfma_f32_16x16x32_bf16(av, bv, acc, 0, 0, 0);
  }
  if (ncol < TH3) {
    const float bias = fp32 ? ((const float*)bih)[ncol] : bf2f(bih[ncol]);
    const int r0 = mt * 16 + (lane >> 4) * 4;
    #pragma unroll
    for (int i = 0; i < 4; ++i)
      gx[(size_t)(r0 + i) * TH3 + ncol] = (f16)(acc[i] + bias);
  }
}

// ---- persistent bidirectional GRU recurrence (wave-autonomous) ------------
// 150 blocks x 4 waves. Block b: d=b&1, g=b>>1. Wave w owns elements
// e0=8g+2w, e1=e0+1 (6 Whh rows in VGPRs, 10 f32/lane over 60 lanes).
// Step loop has NO barriers and NO LDS: poll 600 slots into regs (10/lane),
// dot, 6 xor-reduce chains, lane0 gates + publishes 2 slots.
__global__ __launch_bounds__(256, 1) void gru_rec(const unsigned short* __restrict__ Whh,
                                                  const unsigned short* __restrict__ bhh,
                                                  const f16* __restrict__ gx,
                                                  u64* __restrict__ pub,   // [2][2][600]
                                                  void* __restrict__ outv,
                                                  const int* __restrict__ df) {
  const int tid  = threadIdx.x;
  const int b    = blockIdx.x;
  const int d    = b & 1;
  const int g    = b >> 1;
  const int wv   = tid >> 6;
  const int lane = tid & 63;
  const int e0   = g * 8 + wv * 2;
  const int fp32 = df[0];

  const int rw6[6] = { e0, HDIM + e0, 2 * HDIM + e0,
                       e0 + 1, HDIM + e0 + 1, 2 * HDIM + e0 + 1 };

  // ---- weights: 6 rows x 10 k (k = 10*lane+q), zero for lanes >= 60 -------
  float wreg[6][10];
  #pragma unroll
  for (int r = 0; r < 6; ++r)
    #pragma unroll
    for (int q = 0; q < 10; ++q) wreg[r][q] = 0.f;
  if (lane < 60) {
    #pragma unroll
    for (int r = 0; r < 6; ++r) {
      const size_t rb = (size_t)rw6[r] * HDIM + 10 * lane;
      if (fp32) {
        const float* wp = (const float*)Whh + rb;
        #pragma unroll
        for (int q = 0; q < 10; ++q) wreg[r][q] = wp[q];
      } else {
        const unsigned short* wp = Whh + rb;
        #pragma unroll
        for (int q = 0; q < 10; ++q) wreg[r][q] = bf2f(wp[q]);
      }
    }
  }
  // ---- biases (lane0) -----------------------------------------------------
  float bh[6] = {0.f, 0.f, 0.f, 0.f, 0.f, 0.f};
  if (lane == 0) {
    #pragma unroll
    for (int r = 0; r < 6; ++r)
      bh[r] = fp32 ? ((const float*)bhh)[rw6[r]] : bf2f(bhh[rw6[r]]);
  }

  float hold0 = 0.f, hold1 = 0.f;

  for (int t = 0; t < NSTEP; ++t) {
    // gx prefetch (lane0; issued before the poll, consumed after)
    float gxv[6];
    if (lane == 0) {
      const int rw = (d == 0) ? t : (((t >> 10) << 10) + (1023 - (t & 1023)));
      const f16* p = gx + (size_t)rw * TH3;
      #pragma unroll
      for (int r = 0; r < 6; ++r) gxv[r] = (float)p[rw6[r]];
    }
    // poll all 600 slots into registers: lane l handles k in [10l,10l+10)
    float hv[10];
    #pragma unroll
    for (int q = 0; q < 10; ++q) hv[q] = 0.f;
    if (lane < 60) {
      u64* sp = pub + (size_t)(d * 2 + (t & 1)) * HDIM + 10 * lane;
      const unsigned ut = (unsigned)t;
      unsigned pend = 0x3FFu;
      u64 va[10];
      while (pend) {
        #pragma unroll
        for (int q = 0; q < 10; ++q)
          if (pend & (1u << q))
            va[q] = __hip_atomic_load(sp + q, __ATOMIC_RELAXED, __HIP_MEMORY_SCOPE_AGENT);
        #pragma unroll
        for (int q = 0; q < 10; ++q)
          if ((pend & (1u << q)) && (unsigned)va[q] == ut) {
            union { unsigned u; float f; } cv; cv.u = (unsigned)(va[q] >> 32);
            hv[q] = cv.f;
            pend &= ~(1u << q);
          }
      }
    }
    // 6 row-dots (10 FMA each) + 6 xor-reduce chains (all lanes end w/ sums)
    float s0 = 0.f, s1 = 0.f, s2 = 0.f, s3 = 0.f, s4 = 0.f, s5 = 0.f;
    #pragma unroll
    for (int q = 0; q < 10; ++q) {
      const float h = hv[q];
      s0 += wreg[0][q] * h; s1 += wreg[1][q] * h; s2 += wreg[2][q] * h;
      s3 += wreg[3][q] * h; s4 += wreg[4][q] * h; s5 += wreg[5][q] * h;
    }
    #pragma unroll
    for (int m = 1; m < 64; m <<= 1) {
      s0 += __shfl_xor(s0, m); s1 += __shfl_xor(s1, m); s2 += __shfl_xor(s2, m);
      s3 += __shfl_xor(s3, m); s4 += __shfl_xor(s4, m); s5 += __shfl_xor(s5, m);
    }
    // gates + publish (lane0)
    if (lane == 0) {
      const float r0  = 1.f / (1.f + __expf(-(gxv[0] + s0 + bh[0])));
      const float z0  = 1.f / (1.f + __expf(-(gxv[1] + s1 + bh[1])));
      const float p0  = gxv[2] + r0 * (s2 + bh[2]);
      const float n0  = 1.f - 2.f / (1.f + __expf(2.f * p0));
      const float h0  = n0 + z0 * (hold0 - n0);
      const float r1  = 1.f / (1.f + __expf(-(gxv[3] + s3 + bh[3])));
      const float z1  = 1.f / (1.f + __expf(-(gxv[4] + s4 + bh[4])));
      const float p1  = gxv[5] + r1 * (s5 + bh[5]);
      const float n1  = 1.f - 2.f / (1.f + __expf(2.f * p1));
      const float h1  = n1 + z1 * (hold1 - n1);
      hold0 = h0; hold1 = h1;
      union { float f; unsigned u; } a, c; a.f = h0; c.f = h1;
      u64* dst = pub + (size_t)(d * 2 + ((t + 1) & 1)) * HDIM + e0;
      __hip_atomic_store(dst,     ((u64)a.u << 32) | (unsigned)(t + 1),
                         __ATOMIC_RELAXED, __HIP_MEMORY_SCOPE_AGENT);
      __hip_atomic_store(dst + 1, ((u64)c.u << 32) | (unsigned)(t + 1),
                         __ATOMIC_RELAXED, __HIP_MEMORY_SCOPE_AGENT);
      if (t == NSTEP - 1) {
        const int o = d * HDIM + e0;
        if (fp32) { ((float*)outv)[o] = h0; ((float*)outv)[o + 1] = h1; }
        else { ((unsigned short*)outv)[o] = f2bf(h0);
               ((unsigned short*)outv)[o + 1] = f2bf(h1); }
      }
    }
  }
}

extern "C" void kernel_launch(void* const* d_in, const int* in_sizes, int n_in,
                              void* d_out, int out_size, void* d_ws, size_t ws_size,
                              hipStream_t stream) {
  const unsigned short* ctx  = (const unsigned short*)d_in[0];
  const int*            tags = (const int*)d_in[1];
  const unsigned short* temb = (const unsigned short*)d_in[2];
  const unsigned short* wih  = (const unsigned short*)d_in[3];
  const unsigned short* whh  = (const unsigned short*)d_in[4];
  const unsigned short* bih  = (const unsigned short*)d_in[5];
  const unsigned short* bhh  = (const unsigned short*)d_in[6];

  char* ws = (char*)d_ws;
  unsigned short* X  = (unsigned short*)ws;
  f16*            GX = (f16*)(ws + OFF_GX);
  u64*            PB = (u64*)  (ws + OFF_PB);
  int*            DF = (int*)  (ws + OFF_DF);
  unsigned short* WB = (unsigned short*)(ws + OFF_WB);

  init_k <<<32, 256, 0, stream>>>(ctx, PB, DF);
  embed_k<<<(NROWS * KDIM) / 256, 256, 0, stream>>>(ctx, tags, temb, X, DF);
  wcast_k<<<(TH3 * KDIM) / 256, 256, 0, stream>>>(wih, WB, DF);
  gemm_k <<<dim3(113, 256), 256, 0, stream>>>(X, WB, bih, GX, DF);
  gru_rec<<<150, 256, 0, stream>>>(whh, bhh, GX, PB, d_out, DF);
}

// Round 10
// 34413.919 us; speedup vs baseline: 2.4517x; 2.4517x over previous
//
#include <hip/hip_runtime.h>

// B=16,S=1024,C=509->IN=512,H=600; bidirectional GRU, 16384 serial steps/dir.
//
// R6 (30.0ms, proven): 75 WG/dir x 256thr, agent-scope u64 {ctr|f32} slots,
// LDS-shared poll, 2 barriers/step -> 1.78us/step.
// R9 (84ms): wave-autonomous -> 4x write amp + 4x read fan-in. IC is
// TRANSACTION-throughput bound; share reads, keep publishes line-contiguous.
// R10: R6 protocol, transactions cut 5x: 30 WG/dir x 512thr (20 h each),
// 16B dwordx4 sc1 polls covering 2 self-validating 8B slots each, with
// per-thread deadline fallback (200us) to proven 8B agent atomic loads.
// Stores remain proven 8B agent atomics. Hang-proof: worst case = R6 path.
//
// Workspace:
//   X  @0          16,777,216
//   GX @16,777,216 58,982,400 (fp16)   end 75,759,616
//   PB @75,776,000 [2][2][600]*8 = 19,200
//   DF @75,795,200 256
//   WB @75,795,456 1,843,200

#define HDIM   600
#define TH3    1800
#define NROWS  16384
#define KDIM   512
#define NSTEP  16384
#define KWG    30      // WGs per direction
#define EPW    20      // h elements per WG
#define CH     76
#define HPAD   608

#define OFF_GX 16777216ull
#define OFF_PB 75776000ull
#define OFF_DF 75795200ull
#define OFF_WB 75795456ull

typedef short bf16x8 __attribute__((ext_vector_type(8)));
typedef float f32x4  __attribute__((ext_vector_type(4)));
typedef unsigned uint4v __attribute__((ext_vector_type(4)));
typedef _Float16 f16;
typedef unsigned long long u64;

__device__ __forceinline__ float bf2f(unsigned short u) {
  union { unsigned u32; float f; } v; v.u32 = ((unsigned)u) << 16; return v.f;
}
__device__ __forceinline__ unsigned short f2bf(float f) {
  union { float f; unsigned u; } v; v.f = f;
  unsigned r = (v.u + 0x7FFFu + ((v.u >> 16) & 1u)) >> 16;   // RNE
  return (unsigned short)r;
}
__device__ __forceinline__ float asf(unsigned u) {
  union { unsigned u; float f; } v; v.u = u; return v.f;
}

// ---- init: pub slots + dtype detect ---------------------------------------
__global__ void init_k(const unsigned short* __restrict__ ctx,
                       u64* __restrict__ pub, int* __restrict__ df) {
  int i = blockIdx.x * 256 + threadIdx.x;
  if (i < 2 * 2 * HDIM) {                      // [d][par][600]
    int par = (i / HDIM) & 1;
    pub[i] = par ? 0x00000000FFFFFFFFull : 0ull;   // par0: ctr=0,h=0 (step 0)
  }
  if (blockIdx.x == 0 && threadIdx.x == 0) {
    int bad = 0;
    for (int k = 0; k < 512; ++k) {
      unsigned e = (ctx[2 * k] >> 7) & 0xFFu;
      bad += (e >= 0xF0u) | (e < 0x10u);
    }
    df[0] = (bad > 0) ? 1 : 0;
  }
}

// ---- embed + concat -> X bf16 [16384][512] --------------------------------
__global__ void embed_k(const unsigned short* __restrict__ ctx,
                        const int* __restrict__ tags,
                        const unsigned short* __restrict__ temb,
                        unsigned short* __restrict__ x,
                        const int* __restrict__ df) {
  const int fp32 = df[0];
  int idx = blockIdx.x * 256 + threadIdx.x;
  int row = idx >> 9, j = idx & 511;
  unsigned short v;
  if (fp32) {
    const float* ctxF  = (const float*)ctx;
    const float* tembF = (const float*)temb;
    v = (j < 3) ? f2bf(tembF[tags[row] * 3 + j]) : f2bf(ctxF[row * 509 + (j - 3)]);
  } else {
    v = (j < 3) ? temb[tags[row] * 3 + j] : ctx[row * 509 + (j - 3)];
  }
  x[idx] = v;
}

// ---- W_ih -> bf16 ---------------------------------------------------------
__global__ void wcast_k(const unsigned short* __restrict__ wih,
                        unsigned short* __restrict__ wb,
                        const int* __restrict__ df) {
  const int fp32 = df[0];
  int i = blockIdx.x * 256 + threadIdx.x;
  wb[i] = fp32 ? f2bf(((const float*)wih)[i]) : wih[i];
}

// ---- GEMM: gx[16384][1800] = X @ W_ih^T + b_ih (fp16 out) -----------------
__global__ __launch_bounds__(256) void gemm_k(const unsigned short* __restrict__ X,
                                              const unsigned short* __restrict__ Wb,
                                              const unsigned short* __restrict__ bih,
                                              f16* __restrict__ gx,
                                              const int* __restrict__ df) {
  const int fp32 = df[0];
  const int lane = threadIdx.x & 63;
  const int wv   = threadIdx.x >> 6;
  const int mt   = blockIdx.y * 4 + wv;
  const int nt   = blockIdx.x;
  const int mrow = mt * 16 + (lane & 15);
  const int ncol = nt * 16 + (lane & 15);
  const int koff = (lane >> 4) * 8;
  const int nclamp = (ncol < TH3) ? ncol : (TH3 - 1);

  const bf16x8* ap = (const bf16x8*)(X  + (size_t)mrow   * KDIM + koff);
  const bf16x8* bp = (const bf16x8*)(Wb + (size_t)nclamp * KDIM + koff);

  f32x4 acc = {0.f, 0.f, 0.f, 0.f};
  #pragma unroll
  for (int kc = 0; kc < 16; ++kc) {
    bf16x8 av = ap[kc * 4];
    bf16x8 bv = bp[kc * 4];
    acc = __builtin_amdgcn_mfma_f32_16x16x32_bf16(av, bv, acc, 0, 0, 0);
  }
  if (ncol < TH3) {
    const float bias = fp32 ? ((const float*)bih)[ncol] : bf2f(bih[ncol]);
    const int r0 = mt * 16 + (lane >> 4) * 4;
    #pragma unroll
    for (int i = 0; i < 4; ++i)
      gx[(size_t)(r0 + i) * TH3 + ncol] = (f16)(acc[i] + bias);
  }
}

// ---- persistent bidirectional GRU recurrence ------------------------------
// 60 blocks x 512 thr. Block b: d=b&1, w=b>>1 owns h[20w..20w+20).
// Per step: 300 threads poll 2 slots each via one 16B sc1 load (deadline
// fallback to 8B agent atomics), stash h to LDS; barrier; 480 threads do 60
// row-dots (Whh rows in VGPRs, k-chunk 76, 8 thr/row shfl reduce); barrier;
// 10 threads compute gates for 2 elements each + publish 2 slots (8B agent
// atomic stores, 20 contiguous slots/WG).
__global__ __launch_bounds__(512, 1) void gru_rec(const unsigned short* __restrict__ Whh,
                                                  const unsigned short* __restrict__ bhh,
                                                  const f16* __restrict__ gx,
                                                  u64* __restrict__ pub,   // [2][2][600]
                                                  void* __restrict__ outv,
                                                  const int* __restrict__ df) {
  const int tid = threadIdx.x;
  const int b   = blockIdx.x;
  const int d   = b & 1;
  const int w   = b >> 1;              // 0..29
  const int fp32 = df[0];

  __shared__ __align__(16) float hlds[HPAD];
  __shared__ float ghl[60];

  if (tid < HPAD - HDIM) hlds[HDIM + tid] = 0.f;   // pad stays 0 forever

  const int j = tid >> 3;              // 0..63 (60 used)
  const int c = tid & 7;
  const bool dot_t = (j < 60);
  f32x4 wvr[19];
  if (dot_t) {
    const int gate = j / EPW, i = j % EPW;
    const int row = gate * HDIM + w * EPW + i;
    if (fp32) {
      const float* wp = ((const float*)Whh) + (size_t)row * HDIM + c * CH;
      #pragma unroll
      for (int q = 0; q < 19; ++q) {
        const int kb = c * CH + q * 4;
        f32x4 v;
        if (kb + 3 < HDIM) {
          v = *(const f32x4*)(wp + q * 4);
        } else {
          #pragma unroll
          for (int jj = 0; jj < 4; ++jj)
            v[jj] = (kb + jj < HDIM) ? wp[q * 4 + jj] : 0.f;
        }
        wvr[q] = v;
      }
    } else {
      const unsigned short* wp = Whh + (size_t)row * HDIM + c * CH;
      #pragma unroll
      for (int q = 0; q < 19; ++q) {
        const int kb = c * CH + q * 4;
        f32x4 v;
        if (kb + 3 < HDIM) {
          ushort4 u = *(const ushort4*)(wp + q * 4);
          v[0] = bf2f(u.x); v[1] = bf2f(u.y); v[2] = bf2f(u.z); v[3] = bf2f(u.w);
        } else {
          #pragma unroll
          for (int jj = 0; jj < 4; ++jj)
            v[jj] = (kb + jj < HDIM) ? bf2f(wp[q * 4 + jj]) : 0.f;
        }
        wvr[q] = v;
      }
    }
  }

  // publisher thread p<10 handles elements e0=2p, e1=2p+1 (local)
  float bh[6] = {0.f,0.f,0.f,0.f,0.f,0.f};
  if (tid < 10) {
    #pragma unroll
    for (int r = 0; r < 6; ++r) {
      const int e = 2 * tid + (r >= 3);
      const int gate = r % 3;
      const int col = gate * HDIM + w * EPW + e;
      bh[r] = fp32 ? ((const float*)bhh)[col] : bf2f(bhh[col]);
    }
  }

  float hold0 = 0.f, hold1 = 0.f;
  bool fastok = true;                  // sticky per-thread fallback flag
  const int rec = tid;                 // record index 0..299 (2 slots each)

  for (int t = 0; t < NSTEP; ++t) {
    // gx prefetch (publishers; overlaps poll)
    float gxv[6];
    if (tid < 10) {
      const int rw = (d == 0) ? t : (((t >> 10) << 10) + (1023 - (t & 1023)));
      const f16* p = gx + (size_t)rw * TH3;
      #pragma unroll
      for (int r = 0; r < 6; ++r) {
        const int e = 2 * tid + (r >= 3);
        gxv[r] = (float)p[(r % 3) * HDIM + w * EPW + e];
      }
    }
    // poll: thread (tid<300) validates slots 2*rec, 2*rec+1
    if (tid < 300) {
      u64* sp = pub + (size_t)(d * 2 + (t & 1)) * HDIM + 2 * rec;
      const unsigned ut = (unsigned)t;
      bool g0 = false, g1 = false;
      const u64 t0 = __builtin_amdgcn_s_memrealtime();
      while (!(g0 & g1)) {
        if (fastok) {
          uint4v q;
          asm volatile("global_load_dwordx4 %0, %1, off sc1\n\ts_waitcnt vmcnt(0)"
                       : "=v"(q) : "v"(sp) : "memory");
          if (!g0 && q.x == ut) { hlds[2 * rec]     = asf(q.y); g0 = true; }
          if (!g1 && q.z == ut) { hlds[2 * rec + 1] = asf(q.w); g1 = true; }
          if (!(g0 & g1) && (__builtin_amdgcn_s_memrealtime() - t0) > 20000ull)
            fastok = false;            // ~200us: fall back to proven path
        } else {
          if (!g0) {
            u64 a = __hip_atomic_load(sp, __ATOMIC_RELAXED, __HIP_MEMORY_SCOPE_AGENT);
            if ((unsigned)a == ut) { hlds[2 * rec] = asf((unsigned)(a >> 32)); g0 = true; }
          }
          if (!g1) {
            u64 a = __hip_atomic_load(sp + 1, __ATOMIC_RELAXED, __HIP_MEMORY_SCOPE_AGENT);
            if ((unsigned)a == ut) { hlds[2 * rec + 1] = asf((unsigned)(a >> 32)); g1 = true; }
          }
        }
      }
    }
    __syncthreads();
    // 60 row-dots of length 600 (W in regs, h in LDS, 8 thr/row)
    if (dot_t) {
      float acc = 0.f;
      const float* hp = hlds + c * CH;
      #pragma unroll
      for (int q = 0; q < 19; ++q) {
        f32x4 h4 = *(const f32x4*)(hp + 4 * q);
        acc += wvr[q][0] * h4[0] + wvr[q][1] * h4[1]
             + wvr[q][2] * h4[2] + wvr[q][3] * h4[3];
      }
      acc += __shfl_xor(acc, 1);
      acc += __shfl_xor(acc, 2);
      acc += __shfl_xor(acc, 4);
      if (c == 0) ghl[j] = acc;
    }
    __syncthreads();
    // gates + publish (10 threads, 2 elements each)
    if (tid < 10) {
      const int e0 = 2 * tid;
      const float s0r = ghl[e0],     s0z = ghl[EPW + e0],     s0n = ghl[2 * EPW + e0];
      const float s1r = ghl[e0 + 1], s1z = ghl[EPW + e0 + 1], s1n = ghl[2 * EPW + e0 + 1];
      const float r0  = 1.f / (1.f + __expf(-(gxv[0] + s0r + bh[0])));
      const float z0  = 1.f / (1.f + __expf(-(gxv[1] + s0z + bh[1])));
      const float p0  = gxv[2] + r0 * (s0n + bh[2]);
      const float n0  = 1.f - 2.f / (1.f + __expf(2.f * p0));
      const float h0  = n0 + z0 * (hold0 - n0);
      const float r1  = 1.f / (1.f + __expf(-(gxv[3] + s1r + bh[3])));
      const float z1  = 1.f / (1.f + __expf(-(gxv[4] + s1z + bh[4])));
      const float p1  = gxv[5] + r1 * (s1n + bh[5]);
      const float n1  = 1.f - 2.f / (1.f + __expf(2.f * p1));
      const float h1  = n1 + z1 * (hold1 - n1);
      hold0 = h0; hold1 = h1;
      union { float f; unsigned u; } a, cc; a.f = h0; cc.f = h1;
      u64* dst = pub + (size_t)(d * 2 + ((t + 1) & 1)) * HDIM + w * EPW + e0;
      __hip_atomic_store(dst,     ((u64)a.u  << 32) | (unsigned)(t + 1),
                         __ATOMIC_RELAXED, __HIP_MEMORY_SCOPE_AGENT);
      __hip_atomic_store(dst + 1, ((u64)cc.u << 32) | (unsigned)(t + 1),
                         __ATOMIC_RELAXED, __HIP_MEMORY_SCOPE_AGENT);
      if (t == NSTEP - 1) {
        const int o = d * HDIM + w * EPW + e0;
        if (fp32) { ((float*)outv)[o] = h0; ((float*)outv)[o + 1] = h1; }
        else { ((unsigned short*)outv)[o] = f2bf(h0);
               ((unsigned short*)outv)[o + 1] = f2bf(h1); }
      }
    }
    // no trailing barrier: step-t LDS reads all precede barrier2 (R5 note);
    // ghl reads by publishers finish before they join barrier1 of t+1.
  }
}

extern "C" void kernel_launch(void* const* d_in, const int* in_sizes, int n_in,
                              void* d_out, int out_size, void* d_ws, size_t ws_size,
                              hipStream_t stream) {
  const unsigned short* ctx  = (const unsigned short*)d_in[0];
  const int*            tags = (const int*)d_in[1];
  const unsigned short* temb = (const unsigned short*)d_in[2];
  const unsigned short* wih  = (const unsigned short*)d_in[3];
  const unsigned short* whh  = (const unsigned short*)d_in[4];
  const unsigned short* bih  = (const unsigned short*)d_in[5];
  const unsigned short* bhh  = (const unsigned short*)d_in[6];

  char* ws = (char*)d_ws;
  unsigned short* X  = (unsigned short*)ws;
  f16*            GX = (f16*)(ws + OFF_GX);
  u64*            PB = (u64*)  (ws + OFF_PB);
  int*            DF = (int*)  (ws + OFF_DF);
  unsigned short* WB = (unsigned short*)(ws + OFF_WB);

  init_k <<<32, 256, 0, stream>>>(ctx, PB, DF);
  embed_k<<<(NROWS * KDIM) / 256, 256, 0, stream>>>(ctx, tags, temb, X, DF);
  wcast_k<<<(TH3 * KDIM) / 256, 256, 0, stream>>>(wih, WB, DF);
  gemm_k <<<dim3(113, 256), 256, 0, stream>>>(X, WB, bih, GX, DF);
  gru_rec<<<2 * KWG, 512, 0, stream>>>(whh, bhh, GX, PB, d_out, DF);
}

// Round 11
// 29730.341 us; speedup vs baseline: 2.8380x; 1.1575x over previous
//
#include <hip/hip_runtime.h>

// Problem: B=16, S=1024, C=509 -> IN=512, H=600, bidirectional GRU, one serial
// hidden state over all 16384 steps per direction.
//
// R5: fused data+flag publication (u64 {ctr, f32bits} per h element, parity
// double-buffered, monotonic) -> 2.28 us/step best-case.
// R6 (THIS KERNEL, proven 30.0 ms): busy joint-spin poll -> 1.78 us/step.
// R7 (XCD sc0 asm): hang. R8 (XCD RMW): 44.8ms. R9 (wave-autonomous): 84ms.
// R10 (30WGx512, 16B polls): 34.4ms. All structural alternatives lost;
// reverted to R6 exactly. Per-step cost = IC publish-visibility + observe +
// ~0.4us compute; fan-in and locality are off the critical path (measured).
//
// Workspace layout (total ~74.0 MiB):
//   X   @ 0           : 16384*512*2  = 16,777,216
//   GX  @ 16,777,216  : 16384*1800*2 = 58,982,400 (fp16)   end 75,759,616
//   PUB @ 75,776,000  : 2dir*2par*600*8B = 19,200 (h+counter pairs)
//   DF  @ 75,795,200  : 256 (dtype flag)
//   WB  @ 75,795,456  : 1800*512*2 = 1,843,200 (W_ih bf16)  end 77,638,656

#define HDIM   600
#define TH3    1800
#define NROWS  16384
#define KDIM   512
#define NW     75
#define EPW    8
#define NSTEP  16384
#define CH     76
#define HPAD   608

#define OFF_GX 16777216ull
#define OFF_PB 75776000ull
#define OFF_DF 75795200ull
#define OFF_WB 75795456ull

typedef short bf16x8 __attribute__((ext_vector_type(8)));
typedef float f32x4  __attribute__((ext_vector_type(4)));
typedef _Float16 f16;
typedef unsigned long long u64;

__device__ __forceinline__ float bf2f(unsigned short u) {
  union { unsigned u32; float f; } v; v.u32 = ((unsigned)u) << 16; return v.f;
}
__device__ __forceinline__ unsigned short f2bf(float f) {
  union { float f; unsigned u; } v; v.f = f;
  unsigned r = (v.u + 0x7FFFu + ((v.u >> 16) & 1u)) >> 16;   // RNE
  return (unsigned short)r;
}

// ---- init: seed pub pairs; detect input dtype (bf16 vs fp32) --------------
// parity-0 slots = {counter 0, h=0.0} (valid for step 0), parity-1 = {-1,0}.
__global__ void init_k(const unsigned short* __restrict__ ctx,
                       u64* __restrict__ pub, int* __restrict__ df) {
  int i = blockIdx.x * 256 + threadIdx.x;
  if (i < 2 * 2 * 600) {
    int par = (i / 600) & 1;                   // layout [d][par][600]
    pub[i] = par ? 0x00000000FFFFFFFFull : 0ull;
  }
  if (blockIdx.x == 0 && threadIdx.x == 0) {
    int bad = 0;
    for (int k = 0; k < 512; ++k) {
      unsigned e = (ctx[2 * k] >> 7) & 0xFFu;
      bad += (e >= 0xF0u) | (e < 0x10u);
    }
    df[0] = (bad > 0) ? 1 : 0;
  }
}

// ---- embed + concat -> X bf16 [16384][512] --------------------------------
__global__ void embed_k(const unsigned short* __restrict__ ctx,
                        const int* __restrict__ tags,
                        const unsigned short* __restrict__ temb,
                        unsigned short* __restrict__ x,
                        const int* __restrict__ df) {
  const int fp32 = df[0];
  int idx = blockIdx.x * 256 + threadIdx.x;
  int row = idx >> 9, j = idx & 511;
  unsigned short v;
  if (fp32) {
    const float* ctxF  = (const float*)ctx;
    const float* tembF = (const float*)temb;
    v = (j < 3) ? f2bf(tembF[tags[row] * 3 + j]) : f2bf(ctxF[row * 509 + (j - 3)]);
  } else {
    v = (j < 3) ? temb[tags[row] * 3 + j] : ctx[row * 509 + (j - 3)];
  }
  x[idx] = v;
}

// ---- W_ih -> bf16 copy (no-op copy in bf16 mode) --------------------------
__global__ void wcast_k(const unsigned short* __restrict__ wih,
                        unsigned short* __restrict__ wb,
                        const int* __restrict__ df) {
  const int fp32 = df[0];
  int i = blockIdx.x * 256 + threadIdx.x;            // 1800*512 total
  wb[i] = fp32 ? f2bf(((const float*)wih)[i]) : wih[i];
}

// ---- GEMM: gx[16384][1800] = X @ W_ih^T + b_ih (fp16 out) -----------------
__global__ __launch_bounds__(256) void gemm_k(const unsigned short* __restrict__ X,
                                              const unsigned short* __restrict__ Wb,
                                              const unsigned short* __restrict__ bih,
                                              f16* __restrict__ gx,
                                              const int* __restrict__ df) {
  const int fp32 = df[0];
  const int lane = threadIdx.x & 63;
  const int wv   = threadIdx.x >> 6;
  const int mt   = blockIdx.y * 4 + wv;              // 0..1023
  const int nt   = blockIdx.x;                       // 0..112
  const int mrow = mt * 16 + (lane & 15);
  const int ncol = nt * 16 + (lane & 15);
  const int koff = (lane >> 4) * 8;                  // A[m][k=quad*8+j]
  const int nclamp = (ncol < TH3) ? ncol : (TH3 - 1);

  const bf16x8* ap = (const bf16x8*)(X  + (size_t)mrow   * KDIM + koff);
  const bf16x8* bp = (const bf16x8*)(Wb + (size_t)nclamp * KDIM + koff);

  f32x4 acc = {0.f, 0.f, 0.f, 0.f};
  #pragma unroll
  for (int kc = 0; kc < 16; ++kc) {
    bf16x8 av = ap[kc * 4];
    bf16x8 bv = bp[kc * 4];
    acc = __builtin_amdgcn_mfma_f32_16x16x32_bf16(av, bv, acc, 0, 0, 0);
  }
  if (ncol < TH3) {
    const float bias = fp32 ? ((const float*)bih)[ncol] : bf2f(bih[ncol]);
    const int r0 = mt * 16 + (lane >> 4) * 4;        // C/D: col=lane&15, row=quad*4+reg
    #pragma unroll
    for (int i = 0; i < 4; ++i)
      gx[(size_t)(r0 + i) * TH3 + ncol] = (f16)(acc[i] + bias);
  }
}

// ---- persistent bidirectional GRU recurrence ------------------------------
// 150 WGs (d = bid&1, w = bid>>1). WG owns h[8w..8w+8) of its direction.
// W_hh slice (24 rows x 600, fp32) in VGPRs. Publication: pub[d][par][p]
// (p = element index 0..599) is a u64 {counter | f32bits<<32}; at step t a
// reader polls parity t&1 for counter == t. A slot can only be overwritten
// with t+2 after every WG has finished its step-t gather (data dependency
// through the counters), so "== t" is exact; 8B-aligned atomics are untorn.
__global__ __launch_bounds__(256, 1) void gru_rec(const unsigned short* __restrict__ Whh,
                                                  const unsigned short* __restrict__ bhh,
                                                  const f16* __restrict__ gx,
                                                  u64* __restrict__ pub,      // [2][2][600]
                                                  void* __restrict__ outv,
                                                  const int* __restrict__ df) {
  const int fp32 = df[0];
  const int tid = threadIdx.x;
  const int d   = blockIdx.x & 1;
  const int w   = blockIdx.x >> 1;

  __shared__ __align__(16) float hlds[HPAD];
  __shared__ float ghl[24];

  if (tid < HPAD - HDIM) hlds[HDIM + tid] = 0.f;

  const int r = tid >> 3;            // 0..31 (24 used)
  const int c = tid & 7;
  const bool dot_t = (tid < 192);
  f32x4 wvr[19];
  if (dot_t) {
    const int g = r >> 3, e = r & 7;
    const int row = g * HDIM + w * EPW + e;
    if (fp32) {
      const float* wp = ((const float*)Whh) + (size_t)row * HDIM + c * CH;
      #pragma unroll
      for (int q = 0; q < 19; ++q) {
        const int kb = c * CH + q * 4;
        f32x4 v;
        if (kb + 3 < HDIM) {
          v = *(const f32x4*)(wp + q * 4);
        } else {
          #pragma unroll
          for (int j = 0; j < 4; ++j)
            v[j] = (kb + j < HDIM) ? wp[q * 4 + j] : 0.f;
        }
        wvr[q] = v;
      }
    } else {
      const unsigned short* wp = Whh + (size_t)row * HDIM + c * CH;
      #pragma unroll
      for (int q = 0; q < 19; ++q) {
        const int kb = c * CH + q * 4;
        f32x4 v;
        if (kb + 3 < HDIM) {
          ushort4 u = *(const ushort4*)(wp + q * 4);
          v[0] = bf2f(u.x); v[1] = bf2f(u.y); v[2] = bf2f(u.z); v[3] = bf2f(u.w);
        } else {
          #pragma unroll
          for (int j = 0; j < 4; ++j)
            v[j] = (kb + j < HDIM) ? bf2f(wp[q * 4 + j]) : 0.f;
        }
        wvr[q] = v;
      }
    }
  }

  float bhr = 0.f, bhz = 0.f, bhn = 0.f;
  if (tid < EPW) {
    const int i = w * EPW + tid;
    if (fp32) {
      const float* bF = (const float*)bhh;
      bhr = bF[i]; bhz = bF[HDIM + i]; bhn = bF[2 * HDIM + i];
    } else {
      bhr = bf2f(bhh[i]); bhz = bf2f(bhh[HDIM + i]); bhn = bf2f(bhh[2 * HDIM + i]);
    }
  }

  float hold = 0.f;                  // owner's own h element, carried in-reg

  for (int t = 0; t < NSTEP; ++t) {
    // prefetch this step's gx (independent of h; overlaps poll latency)
    float gxr = 0.f, gxz = 0.f, gxn = 0.f;
    if (tid < EPW) {
      const int rw = (d == 0) ? t : (((t >> 10) << 10) + (1023 - (t & 1023)));
      const f16* p = gx + (size_t)rw * TH3 + w * EPW + tid;
      gxr = (float)p[0]; gxz = (float)p[HDIM]; gxn = (float)p[2 * HDIM];
    }
    // poll+stash: gather h_t from the 600 self-validating pairs into LDS.
    // Busy-poll (no s_sleep -> DPM keeps clocks up); all of a thread's
    // pending slots stay in flight each sweep (joint spin, no serial tail).
    {
      const u64* base = pub + (size_t)(d * 2 + (t & 1)) * 600;
      const unsigned ut = (unsigned)t;
      const int p1 = tid + 256, p2 = tid + 512;
      bool d0 = false, d1 = (p1 >= HDIM), d2 = (p2 >= HDIM);
      while (!(d0 & d1 & d2)) {
        u64 a0 = 0, a1 = 0, a2 = 0;
        if (!d0) a0 = __hip_atomic_load(base + tid, __ATOMIC_RELAXED, __HIP_MEMORY_SCOPE_AGENT);
        if (!d1) a1 = __hip_atomic_load(base + p1,  __ATOMIC_RELAXED, __HIP_MEMORY_SCOPE_AGENT);
        if (!d2) a2 = __hip_atomic_load(base + p2,  __ATOMIC_RELAXED, __HIP_MEMORY_SCOPE_AGENT);
        if (!d0 && (unsigned)a0 == ut) {
          union { unsigned u; float f; } cv; cv.u = (unsigned)(a0 >> 32);
          hlds[tid] = cv.f; d0 = true;
        }
        if (!d1 && (unsigned)a1 == ut) {
          union { unsigned u; float f; } cv; cv.u = (unsigned)(a1 >> 32);
          hlds[p1] = cv.f; d1 = true;
        }
        if (!d2 && (unsigned)a2 == ut) {
          union { unsigned u; float f; } cv; cv.u = (unsigned)(a2 >> 32);
          hlds[p2] = cv.f; d2 = true;
        }
      }
    }
    __syncthreads();
    // 24 row-dots of length 600 (W in regs, h in LDS, 8-way broadcast)
    if (dot_t) {
      float acc = 0.f;
      const float* hp = hlds + c * CH;
      #pragma unroll
      for (int q = 0; q < 19; ++q) {
        f32x4 h4 = *(const f32x4*)(hp + 4 * q);
        acc += wvr[q][0] * h4[0] + wvr[q][1] * h4[1]
             + wvr[q][2] * h4[2] + wvr[q][3] * h4[3];
      }
      acc += __shfl_xor(acc, 1);
      acc += __shfl_xor(acc, 2);
      acc += __shfl_xor(acc, 4);
      if (c == 0) ghl[r] = acc;
    }
    __syncthreads();
    // gates + state update (fp32); publish h_{t+1} immediately (no drain)
    if (tid < EPW) {
      const float rr  = 1.f / (1.f + __expf(-(gxr + ghl[tid] + bhr)));
      const float zz  = 1.f / (1.f + __expf(-(gxz + ghl[8 + tid] + bhz)));
      const float pre = gxn + rr * (ghl[16 + tid] + bhn);
      const float nn  = 1.f - 2.f / (1.f + __expf(2.f * pre));   // tanh(pre)
      const float hn  = nn + zz * (hold - nn);
      hold = hn;
      union { float f; unsigned u; } hv; hv.f = hn;
      const u64 pk = ((u64)hv.u << 32) | (unsigned)(t + 1);
      u64* dst = pub + (size_t)(d * 2 + ((t + 1) & 1)) * 600 + w * EPW + tid;
      __hip_atomic_store(dst, pk, __ATOMIC_RELAXED, __HIP_MEMORY_SCOPE_AGENT);
      if (t == NSTEP - 1) {
        const int o = d * HDIM + w * EPW + tid;
        if (fp32) ((float*)outv)[o] = hn;
        else      ((unsigned short*)outv)[o] = f2bf(hn);
      }
    }
    // NOTE: no barrier here. Fast threads may enter step t+1's poll, but all
    // hlds reads of step t happened before the 2nd barrier, and ghl reads by
    // owners complete before those owners join step t+1's 1st barrier.
  }
}

extern "C" void kernel_launch(void* const* d_in, const int* in_sizes, int n_in,
                              void* d_out, int out_size, void* d_ws, size_t ws_size,
                              hipStream_t stream) {
  const unsigned short* ctx  = (const unsigned short*)d_in[0];
  const int*            tags = (const int*)d_in[1];
  const unsigned short* temb = (const unsigned short*)d_in[2];
  const unsigned short* wih  = (const unsigned short*)d_in[3];
  const unsigned short* whh  = (const unsigned short*)d_in[4];
  const unsigned short* bih  = (const unsigned short*)d_in[5];
  const unsigned short* bhh  = (const unsigned short*)d_in[6];

  char* ws = (char*)d_ws;
  unsigned short* X  = (unsigned short*)ws;
  f16*            GX = (f16*)(ws + OFF_GX);
  u64*            PB = (u64*)  (ws + OFF_PB);
  int*            DF = (int*)  (ws + OFF_DF);
  unsigned short* WB = (unsigned short*)(ws + OFF_WB);

  init_k <<<32, 256, 0, stream>>>(ctx, PB, DF);
  embed_k<<<(NROWS * KDIM) / 256, 256, 0, stream>>>(ctx, tags, temb, X, DF);
  wcast_k<<<(TH3 * KDIM) / 256, 256, 0, stream>>>(wih, WB, DF);
  gemm_k <<<dim3(113, 256), 256, 0, stream>>>(X, WB, bih, GX, DF);
  gru_rec<<<2 * NW, 256, 0, stream>>>(whh, bhh, GX, PB, d_out, DF);
}